// Round 13
// baseline (1997.370 us; speedup 1.0000x reference)
//
#include <hip/hip_runtime.h>
#include <cstdint>
#include <cstddef>

#define BB 2
#define HH 16
#define SS 2048
#define DD 1024
#define DA 64
#define TOPK 32
#define ROWS 4   // q-rows per workgroup (1 per wave)

// ---------------- Projection GEMM: O = X @ W^T (OpenBLAS-sgemm-faithful) ----
// Per output element: strictly sequential FMA over k ascending, kc=384 panels
// combined as ((P0)+P1)+P2.  Tile 64x64, micro 4x4, 4 WGs/CU.
// Round-13 staging rework (FP chains untouched -- LDS layout/timing only):
//  * each thread loads 4 scalar X values of one k-column and stores ONE
//    ds_write_b128 into [k][m] (was 16 scalar ds_write_b32 per float4)
//  * double-buffered 8KB tiles (16KB LDS, still 4 WGs/CU): ONE barrier per
//    16-k step, next-tile global loads issued BEFORE compute (latency hidden
//    under the 512cy FMA block)
// z==0 (Q): O[((b*16+h)*2048+s)*64+da]                      (row-major)
// z==1 (K): O[(((b*16+h)*16 + (da>>2))*2048 + s)*4 + (da&3)] (quad-transposed)
__global__ __launch_bounds__(256, 4) void proj_kernel(const float* __restrict__ X0,
                                                      const float* __restrict__ W0,
                                                      float* __restrict__ O0,
                                                      const float* __restrict__ X1,
                                                      const float* __restrict__ W1,
                                                      float* __restrict__ O1) {
  const float* __restrict__ X = blockIdx.z ? X1 : X0;
  const float* __restrict__ W = blockIdx.z ? W1 : W0;
  float* __restrict__ O       = blockIdx.z ? O1 : O0;

  __shared__ float Ast[2][16][64];   // [buf][k][m], 4KB each
  __shared__ float Bst[2][16][64];
  const int tid = threadIdx.x;
  const int tx = tid & 15, ty = tid >> 4;
  const int m0 = blockIdx.y * 64, n0 = blockIdx.x * 64;

  const int sk = tid & 15;        // k within tile (staging role)
  const int smg = tid >> 4;       // m-group 0..15 (staging role)

  float res[4][4], acc[4][4];
#pragma unroll
  for (int i = 0; i < 4; ++i)
#pragma unroll
    for (int j = 0; j < 4; ++j) { res[i][j] = 0.f; acc[i][j] = 0.f; }

  // prologue: stage tile k0=0 into buf 0
  {
    float xa[4], xb[4];
#pragma unroll
    for (int j = 0; j < 4; ++j) {
      xa[j] = X[(size_t)(m0 + smg * 4 + j) * 1024 + sk];
      xb[j] = W[(size_t)(n0 + smg * 4 + j) * 1024 + sk];
    }
    float4 va; va.x = xa[0]; va.y = xa[1]; va.z = xa[2]; va.w = xa[3];
    float4 vb; vb.x = xb[0]; vb.y = xb[1]; vb.z = xb[2]; vb.w = xb[3];
    *(float4*)&Ast[0][sk][smg * 4] = va;
    *(float4*)&Bst[0][sk][smg * 4] = vb;
  }
  __syncthreads();

  int cur = 0;
  for (int k0 = 0; k0 < 1024; k0 += 16) {
    if (k0 == 384 || k0 == 768) {   // OpenBLAS kc-panel boundary
#pragma unroll
      for (int i = 0; i < 4; ++i)
#pragma unroll
        for (int j = 0; j < 4; ++j) { res[i][j] = __fadd_rn(res[i][j], acc[i][j]); acc[i][j] = 0.f; }
    }

    const bool more = (k0 + 16) < 1024;
    float ya[4], yb[4];
    if (more) {                     // issue next-tile loads before compute
#pragma unroll
      for (int j = 0; j < 4; ++j) {
        ya[j] = X[(size_t)(m0 + smg * 4 + j) * 1024 + (k0 + 16) + sk];
        yb[j] = W[(size_t)(n0 + smg * 4 + j) * 1024 + (k0 + 16) + sk];
      }
    }

#pragma unroll
    for (int k = 0; k < 16; ++k) {
      const float4 av4 = *(const float4*)&Ast[cur][k][ty * 4];
      const float4 bv4 = *(const float4*)&Bst[cur][k][tx * 4];
      const float av[4] = {av4.x, av4.y, av4.z, av4.w};
      const float bv[4] = {bv4.x, bv4.y, bv4.z, bv4.w};
#pragma unroll
      for (int i = 0; i < 4; ++i)
#pragma unroll
        for (int j = 0; j < 4; ++j) acc[i][j] = fmaf(av[i], bv[j], acc[i][j]);
    }

    if (more) {                     // write next tile into the other buffer
      float4 va; va.x = ya[0]; va.y = ya[1]; va.z = ya[2]; va.w = ya[3];
      float4 vb; vb.x = yb[0]; vb.y = yb[1]; vb.z = yb[2]; vb.w = yb[3];
      *(float4*)&Ast[cur ^ 1][sk][smg * 4] = va;
      *(float4*)&Bst[cur ^ 1][sk][smg * 4] = vb;
    }
    __syncthreads();                // one barrier per step (dbuf)
    cur ^= 1;
  }

#pragma unroll
  for (int i = 0; i < 4; ++i) {
    const int m = m0 + ty * 4 + i;
    const int b = m >> 11, s = m & 2047;
#pragma unroll
    for (int j = 0; j < 4; ++j) {
      const int n = n0 + tx * 4 + j;
      const int h = n >> 6, da = n & 63;
      const float v = __fadd_rn(res[i][j], acc[i][j]);
      if (blockIdx.z) {
        // K: quad-transposed layout [bh][da>>2][s][da&3]
        O[(((size_t)((b * 16 + h) * 16 + (da >> 2)) * 2048 + s) << 2) + (da & 3)] = v;
      } else {
        O[(((size_t)(b * 16 + h) * 2048 + s) * 64 + da)] = v;
      }
    }
  }
}

// ---------------- Fused topk-attention (np.einsum-faithful f32 scores) ------
// EXACT r8 kernel (684us): bit-identical per-(row,key) chain (SSE 4-lane,
// no FMA, groups of 16 ascending, 4-blocks descending, (a0+a1)+(a2+a3),
// *0.125).  WG = 256 threads (4 waves) per (bh, 4 q-rows).  LDS 32768 B.
// Settled structure per r1-r12: ROWS=4/WG=256 is the local optimum
// (occupancy pinned ~16 waves/CU; register prefetch spills; ROWS=8 breaks
// Q scalarization; packed math not bit-exact; ROWS=2 doubles gather work).
__global__ __launch_bounds__(256) void attn_kernel(const float* __restrict__ Qp,
                                                   const float* __restrict__ Kp,
                                                   const float* __restrict__ V,
                                                   float* __restrict__ out) {
  __shared__ float Srow[ROWS * 2048];   // 32 KB score block (+aliased lists)

  const int tid = threadIdx.x;
  const int w = tid >> 6, l = tid & 63;
  // bijective XCD-chunk swizzle (nwg = 16384, divisible by 8 XCDs)
  const int nwg = BB * HH * (SS / ROWS);
  const int bidx = (int)blockIdx.x;
  const int swz = (bidx & 7) * (nwg >> 3) + (bidx >> 3);
  const int bh = swz >> 9;
  const int rb = swz & 511;
  const int b = bh >> 4, h = bh & 15;
  const int r0 = rb * ROWS;

  // quad-transposed K panel for this (b,h): [16 quads][2048 keys][4 floats]
  const float* Ktb = Kp + (size_t)bh * (16 * 2048 * 4);

  // ----- score phase: each thread handles keys tid + 256*c, c = 0..7 --------
#pragma unroll 1
  for (int c = 0; c < 8; ++c) {
    const int key = tid + c * 256;

    float acc[ROWS][4];                 // [row][sse-lane], static-indexed
#pragma unroll
    for (int r = 0; r < ROWS; ++r)
#pragma unroll
      for (int j = 0; j < 4; ++j) acc[r][j] = 0.f;

#pragma unroll
    for (int g = 0; g < 4; ++g) {       // groups of 16, ascending
      float4 kt[4];                     // one 64B line of K (coalesced loads)
#pragma unroll
      for (int i = 0; i < 4; ++i)
        kt[i] = *(const float4*)(Ktb + (((size_t)(g * 4 + i) * 2048 + key) << 2));
#pragma unroll
      for (int r = 0; r < ROWS; ++r) {
        // wave-uniform Q addresses -> scalar loads
        const float4* qp4 = (const float4*)(Qp + ((size_t)bh * SS + r0 + r) * DA);
        float4 q4[4];
#pragma unroll
        for (int i = 0; i < 4; ++i) q4[i] = qp4[g * 4 + i];
#pragma unroll
        for (int blk = 3; blk >= 0; --blk) {   // 4-blocks DESCENDING in group
          acc[r][0] = __fadd_rn(acc[r][0], __fmul_rn(q4[blk].x, kt[blk].x));
          acc[r][1] = __fadd_rn(acc[r][1], __fmul_rn(q4[blk].y, kt[blk].y));
          acc[r][2] = __fadd_rn(acc[r][2], __fmul_rn(q4[blk].z, kt[blk].z));
          acc[r][3] = __fadd_rn(acc[r][3], __fmul_rn(q4[blk].w, kt[blk].w));
        }
      }
    }
#pragma unroll
    for (int r = 0; r < ROWS; ++r) {
      const float s = __fadd_rn(__fadd_rn(acc[r][0], acc[r][1]),
                                __fadd_rn(acc[r][2], acc[r][3]));
      Srow[r * 2048 + key] = s * 0.125f;
    }
  }
  __syncthreads();

  const float* Vh = V + (size_t)b * SS * DD + h * DA;
  float* outh = out + ((size_t)(b * SS + r0 + w)) * DD + h * DA;

  // ----- per-wave: one row (r = w): exact top-32, softmax, sparse PV --------
  {
    const int r = w;
    float sv[32];
#pragma unroll
    for (int i = 0; i < 32; ++i) sv[i] = Srow[r * 2048 + 64 * i + l];
    // From here on, this wave's Srow slice is dead: reuse the first 128
    // floats of it as the survivor (weight,key) lists.
    float* wl = &Srow[r * 2048];        // [0..63]  survivor weights
    float* kl = &Srow[r * 2048 + 64];   // [64..127] survivor keys (bit-punned)

    float mx = sv[0], mn = sv[0];
#pragma unroll
    for (int i = 1; i < 32; ++i) { mx = fmaxf(mx, sv[i]); mn = fminf(mn, sv[i]); }
#pragma unroll
    for (int off = 32; off >= 1; off >>= 1) {
      mx = fmaxf(mx, __shfl_xor(mx, off));
      mn = fminf(mn, __shfl_xor(mn, off));
    }

    // bisection for the exact 32nd-largest score value.
    float lo = mn, hi = mx + 1.0f;
    float cutoff = mn;
    for (int it = 0; ; ++it) {
      const float mid = 0.5f * (lo + hi);
      if (it >= 64 || !(mid > lo && mid < hi)) { cutoff = lo; break; }
      int c = 0;
#pragma unroll
      for (int i = 0; i < 32; ++i)
        c += (int)__popcll(__ballot(sv[i] >= mid));
      if (c == TOPK) {
        float cm = 3.0e38f;
#pragma unroll
        for (int i = 0; i < 32; ++i) if (sv[i] >= mid) cm = fminf(cm, sv[i]);
#pragma unroll
        for (int off = 32; off >= 1; off >>= 1) cm = fminf(cm, __shfl_xor(cm, off));
        cutoff = cm;
        break;
      }
      if (c > TOPK) lo = mid; else hi = mid;
    }

    // weights on kept entries (ties at cutoff kept, matching scores>=cutoff)
    float wv[32];
    float dpart = 0.f;
    int ckept = 0;
#pragma unroll
    for (int i = 0; i < 32; ++i) {
      const bool keep = (sv[i] >= cutoff);
      ckept += (int)__popcll(__ballot(keep));
      const float e = keep ? __expf(sv[i] - mx) : 0.f;
      wv[i] = e;
      dpart += e;
    }
    float denom = dpart;
#pragma unroll
    for (int off = 32; off >= 1; off >>= 1) denom += __shfl_xor(denom, off);
    const float inv_denom = 1.0f / denom;

    float e = 0.f;
    if (ckept <= 64) {
      // ballot compaction of survivors into the aliased LDS lists (ascending k)
      int base = 0;
#pragma unroll
      for (int i = 0; i < 32; ++i) {
        const unsigned long long mball = __ballot(wv[i] > 0.f);
        if (wv[i] > 0.f) {
          const int pos = base + (int)__popcll(mball & ((1ull << l) - 1ull));
          wl[pos] = wv[i];
          kl[pos] = __int_as_float(64 * i + l);
        }
        base += (int)__popcll(mball);
      }
      asm volatile("s_waitcnt lgkmcnt(0)" ::: "memory");
      // PV gather, batched x8: 8 independent V loads in flight per batch.
      // fma chain order (ascending survivor index) preserved bit-identically.
      int i = 0;
      for (; i + 8 <= ckept; i += 8) {
        float ww[8]; int kk[8];
#pragma unroll
        for (int u = 0; u < 8; ++u) { ww[u] = wl[i + u]; kk[u] = __float_as_int(kl[i + u]); }
        float vv[8];
#pragma unroll
        for (int u = 0; u < 8; ++u) vv[u] = Vh[(size_t)kk[u] * DD + l];
#pragma unroll
        for (int u = 0; u < 8; ++u) e = fmaf(ww[u], vv[u], e);
      }
      for (; i < ckept; ++i) {
        const float ww = wl[i];
        const int kk = __float_as_int(kl[i]);
        e = fmaf(ww, Vh[(size_t)kk * DD + l], e);
      }
    } else {
      // pathological-tie fallback: dense accumulation (own row only)
#pragma unroll
      for (int i = 0; i < 32; ++i) Srow[r * 2048 + 64 * i + l] = wv[i];
      asm volatile("s_waitcnt lgkmcnt(0)" ::: "memory");
      for (int k = 0; k < 2048; ++k) {
        const float ww = Srow[r * 2048 + k];
        if (ww > 0.f) e = fmaf(ww, Vh[(size_t)k * DD + l], e);
      }
    }
    outh[l] = e * inv_denom;
  }
}

extern "C" void kernel_launch(void* const* d_in, const int* in_sizes, int n_in,
                              void* d_out, int out_size, void* d_ws, size_t ws_size,
                              hipStream_t stream) {
  const float* query = (const float*)d_in[0];
  const float* key   = (const float*)d_in[1];
  const float* value = (const float*)d_in[2];
  const float* Wq    = (const float*)d_in[3];
  const float* Wk    = (const float*)d_in[4];
  float* out = (float*)d_out;

  float* Qp = (float*)d_ws;                                  // 16.8 MB
  float* Kp = Qp + (size_t)BB * HH * SS * DA;                // 16.8 MB (transposed)

  proj_kernel<<<dim3(16, 64, 2), 256, 0, stream>>>(query, Wq, Qp, key, Wk, Kp);
  attn_kernel<<<dim3(BB * HH * (SS / ROWS)), 256, 0, stream>>>(Qp, Kp, value, out);
}

// Round 14
// 944.692 us; speedup vs baseline: 2.1143x; 2.1143x over previous
//
#include <hip/hip_runtime.h>
#include <cstdint>
#include <cstddef>

#define BB 2
#define HH 16
#define SS 2048
#define DD 1024
#define DA 64
#define TOPK 32
#define ROWS 4   // q-rows per workgroup (1 per wave)

// ---------------- Projection GEMM: O = X @ W^T (OpenBLAS-sgemm-faithful) ----
// Per output element: strictly sequential FMA over k ascending, kc=384 panels
// combined as ((P0)+P1)+P2.  Tile 64x64, micro 4x4, 4 WGs/CU.
// Round-14: REVERT to the proven r8 staging (r13's b128/[k][m] rework spilled
// at the 64-VGPR band AND hit a 16-way LDS write conflict, 5.9e7 counts).
// One safe tweak kept: Ast/Bst padded [16][65] -- write bank was srow%32
// (4-way, 16 banks idle); pad spreads to (4*skg+i+srow)%32 (~2.3-way).
// LDS addressing only: FP chains, registers, barriers all as the 175us build.
// z==0 (Q): O[((b*16+h)*2048+s)*64+da]                      (row-major)
// z==1 (K): O[(((b*16+h)*16 + (da>>2))*2048 + s)*4 + (da&3)] (quad-transposed)
__global__ __launch_bounds__(256, 4) void proj_kernel(const float* __restrict__ X0,
                                                      const float* __restrict__ W0,
                                                      float* __restrict__ O0,
                                                      const float* __restrict__ X1,
                                                      const float* __restrict__ W1,
                                                      float* __restrict__ O1) {
  const float* __restrict__ X = blockIdx.z ? X1 : X0;
  const float* __restrict__ W = blockIdx.z ? W1 : W0;
  float* __restrict__ O       = blockIdx.z ? O1 : O0;

  __shared__ float Ast[16][65];   // +1 pad: write conflicts 4-way -> ~2.3-way
  __shared__ float Bst[16][65];
  const int tid = threadIdx.x;
  const int tx = tid & 15, ty = tid >> 4;
  const int m0 = blockIdx.y * 64, n0 = blockIdx.x * 64;

  float res[4][4], acc[4][4];
#pragma unroll
  for (int i = 0; i < 4; ++i)
#pragma unroll
    for (int j = 0; j < 4; ++j) { res[i][j] = 0.f; acc[i][j] = 0.f; }

  const int srow = tid >> 2, skg = tid & 3;   // staging: one float4 per thread
  for (int k0 = 0; k0 < 1024; k0 += 16) {
    if (k0 == 384 || k0 == 768) {   // OpenBLAS kc-panel boundary
#pragma unroll
      for (int i = 0; i < 4; ++i)
#pragma unroll
        for (int j = 0; j < 4; ++j) { res[i][j] = __fadd_rn(res[i][j], acc[i][j]); acc[i][j] = 0.f; }
    }
    {
      const float4 va = *(const float4*)(X + (size_t)(m0 + srow) * 1024 + k0 + skg * 4);
      Ast[skg * 4 + 0][srow] = va.x; Ast[skg * 4 + 1][srow] = va.y;
      Ast[skg * 4 + 2][srow] = va.z; Ast[skg * 4 + 3][srow] = va.w;
      const float4 vb = *(const float4*)(W + (size_t)(n0 + srow) * 1024 + k0 + skg * 4);
      Bst[skg * 4 + 0][srow] = vb.x; Bst[skg * 4 + 1][srow] = vb.y;
      Bst[skg * 4 + 2][srow] = vb.z; Bst[skg * 4 + 3][srow] = vb.w;
    }
    __syncthreads();
#pragma unroll
    for (int k = 0; k < 16; ++k) {
      float av[4], bv[4];
#pragma unroll
      for (int i = 0; i < 4; ++i) av[i] = Ast[k][ty * 4 + i];
#pragma unroll
      for (int j = 0; j < 4; ++j) bv[j] = Bst[k][tx * 4 + j];
#pragma unroll
      for (int i = 0; i < 4; ++i)
#pragma unroll
        for (int j = 0; j < 4; ++j) acc[i][j] = fmaf(av[i], bv[j], acc[i][j]);
    }
    __syncthreads();
  }

#pragma unroll
  for (int i = 0; i < 4; ++i) {
    const int m = m0 + ty * 4 + i;
    const int b = m >> 11, s = m & 2047;
#pragma unroll
    for (int j = 0; j < 4; ++j) {
      const int n = n0 + tx * 4 + j;
      const int h = n >> 6, da = n & 63;
      const float v = __fadd_rn(res[i][j], acc[i][j]);
      if (blockIdx.z) {
        // K: quad-transposed layout [bh][da>>2][s][da&3]
        O[(((size_t)((b * 16 + h) * 16 + (da >> 2)) * 2048 + s) << 2) + (da & 3)] = v;
      } else {
        O[(((size_t)(b * 16 + h) * 2048 + s) * 64 + da)] = v;
      }
    }
  }
}

// ---------------- Fused topk-attention (np.einsum-faithful f32 scores) ------
// EXACT r8 kernel (684us): bit-identical per-(row,key) chain (SSE 4-lane,
// no FMA, groups of 16 ascending, 4-blocks descending, (a0+a1)+(a2+a3),
// *0.125).  WG = 256 threads (4 waves) per (bh, 4 q-rows).  LDS 32768 B.
// Settled structure per r1-r12: ROWS=4/WG=256 is the local optimum
// (occupancy pinned ~16 waves/CU; register prefetch spills; ROWS=8 breaks
// Q scalarization; packed math not bit-exact; ROWS=2 doubles gather work).
__global__ __launch_bounds__(256) void attn_kernel(const float* __restrict__ Qp,
                                                   const float* __restrict__ Kp,
                                                   const float* __restrict__ V,
                                                   float* __restrict__ out) {
  __shared__ float Srow[ROWS * 2048];   // 32 KB score block (+aliased lists)

  const int tid = threadIdx.x;
  const int w = tid >> 6, l = tid & 63;
  // bijective XCD-chunk swizzle (nwg = 16384, divisible by 8 XCDs)
  const int nwg = BB * HH * (SS / ROWS);
  const int bidx = (int)blockIdx.x;
  const int swz = (bidx & 7) * (nwg >> 3) + (bidx >> 3);
  const int bh = swz >> 9;
  const int rb = swz & 511;
  const int b = bh >> 4, h = bh & 15;
  const int r0 = rb * ROWS;

  // quad-transposed K panel for this (b,h): [16 quads][2048 keys][4 floats]
  const float* Ktb = Kp + (size_t)bh * (16 * 2048 * 4);

  // ----- score phase: each thread handles keys tid + 256*c, c = 0..7 --------
#pragma unroll 1
  for (int c = 0; c < 8; ++c) {
    const int key = tid + c * 256;

    float acc[ROWS][4];                 // [row][sse-lane], static-indexed
#pragma unroll
    for (int r = 0; r < ROWS; ++r)
#pragma unroll
      for (int j = 0; j < 4; ++j) acc[r][j] = 0.f;

#pragma unroll
    for (int g = 0; g < 4; ++g) {       // groups of 16, ascending
      float4 kt[4];                     // one 64B line of K (coalesced loads)
#pragma unroll
      for (int i = 0; i < 4; ++i)
        kt[i] = *(const float4*)(Ktb + (((size_t)(g * 4 + i) * 2048 + key) << 2));
#pragma unroll
      for (int r = 0; r < ROWS; ++r) {
        // wave-uniform Q addresses -> scalar loads
        const float4* qp4 = (const float4*)(Qp + ((size_t)bh * SS + r0 + r) * DA);
        float4 q4[4];
#pragma unroll
        for (int i = 0; i < 4; ++i) q4[i] = qp4[g * 4 + i];
#pragma unroll
        for (int blk = 3; blk >= 0; --blk) {   // 4-blocks DESCENDING in group
          acc[r][0] = __fadd_rn(acc[r][0], __fmul_rn(q4[blk].x, kt[blk].x));
          acc[r][1] = __fadd_rn(acc[r][1], __fmul_rn(q4[blk].y, kt[blk].y));
          acc[r][2] = __fadd_rn(acc[r][2], __fmul_rn(q4[blk].z, kt[blk].z));
          acc[r][3] = __fadd_rn(acc[r][3], __fmul_rn(q4[blk].w, kt[blk].w));
        }
      }
    }
#pragma unroll
    for (int r = 0; r < ROWS; ++r) {
      const float s = __fadd_rn(__fadd_rn(acc[r][0], acc[r][1]),
                                __fadd_rn(acc[r][2], acc[r][3]));
      Srow[r * 2048 + key] = s * 0.125f;
    }
  }
  __syncthreads();

  const float* Vh = V + (size_t)b * SS * DD + h * DA;
  float* outh = out + ((size_t)(b * SS + r0 + w)) * DD + h * DA;

  // ----- per-wave: one row (r = w): exact top-32, softmax, sparse PV --------
  {
    const int r = w;
    float sv[32];
#pragma unroll
    for (int i = 0; i < 32; ++i) sv[i] = Srow[r * 2048 + 64 * i + l];
    // From here on, this wave's Srow slice is dead: reuse the first 128
    // floats of it as the survivor (weight,key) lists.
    float* wl = &Srow[r * 2048];        // [0..63]  survivor weights
    float* kl = &Srow[r * 2048 + 64];   // [64..127] survivor keys (bit-punned)

    float mx = sv[0], mn = sv[0];
#pragma unroll
    for (int i = 1; i < 32; ++i) { mx = fmaxf(mx, sv[i]); mn = fminf(mn, sv[i]); }
#pragma unroll
    for (int off = 32; off >= 1; off >>= 1) {
      mx = fmaxf(mx, __shfl_xor(mx, off));
      mn = fminf(mn, __shfl_xor(mn, off));
    }

    // bisection for the exact 32nd-largest score value.
    float lo = mn, hi = mx + 1.0f;
    float cutoff = mn;
    for (int it = 0; ; ++it) {
      const float mid = 0.5f * (lo + hi);
      if (it >= 64 || !(mid > lo && mid < hi)) { cutoff = lo; break; }
      int c = 0;
#pragma unroll
      for (int i = 0; i < 32; ++i)
        c += (int)__popcll(__ballot(sv[i] >= mid));
      if (c == TOPK) {
        float cm = 3.0e38f;
#pragma unroll
        for (int i = 0; i < 32; ++i) if (sv[i] >= mid) cm = fminf(cm, sv[i]);
#pragma unroll
        for (int off = 32; off >= 1; off >>= 1) cm = fminf(cm, __shfl_xor(cm, off));
        cutoff = cm;
        break;
      }
      if (c > TOPK) lo = mid; else hi = mid;
    }

    // weights on kept entries (ties at cutoff kept, matching scores>=cutoff)
    float wv[32];
    float dpart = 0.f;
    int ckept = 0;
#pragma unroll
    for (int i = 0; i < 32; ++i) {
      const bool keep = (sv[i] >= cutoff);
      ckept += (int)__popcll(__ballot(keep));
      const float e = keep ? __expf(sv[i] - mx) : 0.f;
      wv[i] = e;
      dpart += e;
    }
    float denom = dpart;
#pragma unroll
    for (int off = 32; off >= 1; off >>= 1) denom += __shfl_xor(denom, off);
    const float inv_denom = 1.0f / denom;

    float e = 0.f;
    if (ckept <= 64) {
      // ballot compaction of survivors into the aliased LDS lists (ascending k)
      int base = 0;
#pragma unroll
      for (int i = 0; i < 32; ++i) {
        const unsigned long long mball = __ballot(wv[i] > 0.f);
        if (wv[i] > 0.f) {
          const int pos = base + (int)__popcll(mball & ((1ull << l) - 1ull));
          wl[pos] = wv[i];
          kl[pos] = __int_as_float(64 * i + l);
        }
        base += (int)__popcll(mball);
      }
      asm volatile("s_waitcnt lgkmcnt(0)" ::: "memory");
      // PV gather, batched x8: 8 independent V loads in flight per batch.
      // fma chain order (ascending survivor index) preserved bit-identically.
      int i = 0;
      for (; i + 8 <= ckept; i += 8) {
        float ww[8]; int kk[8];
#pragma unroll
        for (int u = 0; u < 8; ++u) { ww[u] = wl[i + u]; kk[u] = __float_as_int(kl[i + u]); }
        float vv[8];
#pragma unroll
        for (int u = 0; u < 8; ++u) vv[u] = Vh[(size_t)kk[u] * DD + l];
#pragma unroll
        for (int u = 0; u < 8; ++u) e = fmaf(ww[u], vv[u], e);
      }
      for (; i < ckept; ++i) {
        const float ww = wl[i];
        const int kk = __float_as_int(kl[i]);
        e = fmaf(ww, Vh[(size_t)kk * DD + l], e);
      }
    } else {
      // pathological-tie fallback: dense accumulation (own row only)
#pragma unroll
      for (int i = 0; i < 32; ++i) Srow[r * 2048 + 64 * i + l] = wv[i];
      asm volatile("s_waitcnt lgkmcnt(0)" ::: "memory");
      for (int k = 0; k < 2048; ++k) {
        const float ww = Srow[r * 2048 + k];
        if (ww > 0.f) e = fmaf(ww, Vh[(size_t)k * DD + l], e);
      }
    }
    outh[l] = e * inv_denom;
  }
}

extern "C" void kernel_launch(void* const* d_in, const int* in_sizes, int n_in,
                              void* d_out, int out_size, void* d_ws, size_t ws_size,
                              hipStream_t stream) {
  const float* query = (const float*)d_in[0];
  const float* key   = (const float*)d_in[1];
  const float* value = (const float*)d_in[2];
  const float* Wq    = (const float*)d_in[3];
  const float* Wk    = (const float*)d_in[4];
  float* out = (float*)d_out;

  float* Qp = (float*)d_ws;                                  // 16.8 MB
  float* Kp = Qp + (size_t)BB * HH * SS * DA;                // 16.8 MB (transposed)

  proj_kernel<<<dim3(16, 64, 2), 256, 0, stream>>>(query, Wq, Qp, key, Wk, Kp);
  attn_kernel<<<dim3(BB * HH * (SS / ROWS)), 256, 0, stream>>>(Qp, Kp, value, out);
}

// Round 15
// 876.290 us; speedup vs baseline: 2.2793x; 1.0781x over previous
//
#include <hip/hip_runtime.h>
#include <cstdint>
#include <cstddef>

#define BB 2
#define HH 16
#define SS 2048
#define DD 1024
#define DA 64
#define TOPK 32
#define ROWS 4   // q-rows per workgroup (1 per wave)

// ---------------- Projection GEMM: O = X @ W^T (OpenBLAS-sgemm-faithful) ----
// Per output element: strictly sequential FMA over k ascending, kc=384 panels
// combined as ((P0)+P1)+P2.  Tile 64x64, micro 4x4, 4 WGs/CU.
// Round-15: UNPADDED [16][64] (r14's +1 pad broke ds_read_b128 alignment:
// -60us).  One change vs the proven r8 staging: double-buffered LDS tiles,
// ONE barrier per k-step (was 2).  Per step: stage t+1 into buf^1 (float4
// global load -> immediate scalar ds_writes, nothing held across compute),
// compute t from buf, barrier.  Barrier t separates compute-read(buf)@t from
// overwrite@t+2 and write(buf^1)@t from read@t+1: correct with one barrier.
// FP chains untouched (kc boundaries at 384/768 in original positions).
// z==0 (Q): O[((b*16+h)*2048+s)*64+da]                      (row-major)
// z==1 (K): O[(((b*16+h)*16 + (da>>2))*2048 + s)*4 + (da&3)] (quad-transposed)
__global__ __launch_bounds__(256, 4) void proj_kernel(const float* __restrict__ X0,
                                                      const float* __restrict__ W0,
                                                      float* __restrict__ O0,
                                                      const float* __restrict__ X1,
                                                      const float* __restrict__ W1,
                                                      float* __restrict__ O1) {
  const float* __restrict__ X = blockIdx.z ? X1 : X0;
  const float* __restrict__ W = blockIdx.z ? W1 : W0;
  float* __restrict__ O       = blockIdx.z ? O1 : O0;

  __shared__ float Ast[2][16][64];
  __shared__ float Bst[2][16][64];
  const int tid = threadIdx.x;
  const int tx = tid & 15, ty = tid >> 4;
  const int m0 = blockIdx.y * 64, n0 = blockIdx.x * 64;

  float res[4][4], acc[4][4];
#pragma unroll
  for (int i = 0; i < 4; ++i)
#pragma unroll
    for (int j = 0; j < 4; ++j) { res[i][j] = 0.f; acc[i][j] = 0.f; }

  const int srow = tid >> 2, skg = tid & 3;   // staging: one float4 per thread

#define STAGE(buf, kk)                                                        \
  {                                                                           \
    const float4 va = *(const float4*)(X + (size_t)(m0 + srow) * 1024 + (kk) + skg * 4); \
    Ast[buf][skg * 4 + 0][srow] = va.x; Ast[buf][skg * 4 + 1][srow] = va.y;   \
    Ast[buf][skg * 4 + 2][srow] = va.z; Ast[buf][skg * 4 + 3][srow] = va.w;   \
    const float4 vb = *(const float4*)(W + (size_t)(n0 + srow) * 1024 + (kk) + skg * 4); \
    Bst[buf][skg * 4 + 0][srow] = vb.x; Bst[buf][skg * 4 + 1][srow] = vb.y;   \
    Bst[buf][skg * 4 + 2][srow] = vb.z; Bst[buf][skg * 4 + 3][srow] = vb.w;   \
  }

  STAGE(0, 0);
  __syncthreads();

#pragma unroll 1
  for (int t = 0; t < 64; ++t) {
    const int k0 = t * 16;
    if (k0 == 384 || k0 == 768) {   // OpenBLAS kc-panel boundary
#pragma unroll
      for (int i = 0; i < 4; ++i)
#pragma unroll
        for (int j = 0; j < 4; ++j) { res[i][j] = __fadd_rn(res[i][j], acc[i][j]); acc[i][j] = 0.f; }
    }
    const int cur = t & 1;
    if (t + 1 < 64) STAGE(cur ^ 1, k0 + 16);   // next tile in flight
#pragma unroll
    for (int k = 0; k < 16; ++k) {
      float av[4], bv[4];
#pragma unroll
      for (int i = 0; i < 4; ++i) av[i] = Ast[cur][k][ty * 4 + i];
#pragma unroll
      for (int j = 0; j < 4; ++j) bv[j] = Bst[cur][k][tx * 4 + j];
#pragma unroll
      for (int i = 0; i < 4; ++i)
#pragma unroll
        for (int j = 0; j < 4; ++j) acc[i][j] = fmaf(av[i], bv[j], acc[i][j]);
    }
    __syncthreads();                // single barrier per step (dbuf)
  }
#undef STAGE

#pragma unroll
  for (int i = 0; i < 4; ++i) {
    const int m = m0 + ty * 4 + i;
    const int b = m >> 11, s = m & 2047;
#pragma unroll
    for (int j = 0; j < 4; ++j) {
      const int n = n0 + tx * 4 + j;
      const int h = n >> 6, da = n & 63;
      const float v = __fadd_rn(res[i][j], acc[i][j]);
      if (blockIdx.z) {
        // K: quad-transposed layout [bh][da>>2][s][da&3]
        O[(((size_t)((b * 16 + h) * 16 + (da >> 2)) * 2048 + s) << 2) + (da & 3)] = v;
      } else {
        O[(((size_t)(b * 16 + h) * 2048 + s) * 64 + da)] = v;
      }
    }
  }
}

// ---------------- Fused topk-attention (np.einsum-faithful f32 scores) ------
// EXACT r8 kernel (684us): bit-identical per-(row,key) chain (SSE 4-lane,
// no FMA, groups of 16 ascending, 4-blocks descending, (a0+a1)+(a2+a3),
// *0.125).  WG = 256 threads (4 waves) per (bh, 4 q-rows).  LDS 32768 B.
// Settled per r1-r12 (+quantum finding): VGPR quantum is 64 on a 256 pool,
// so this 48-VGPR body is pinned at 4 waves/SIMD; register prefetch spills
// at the 64 band; ROWS=8 breaks Q scalarization; packed math not bit-exact;
// ROWS=2 doubles gather work.  ROWS=4/WG=256 is the optimum.
__global__ __launch_bounds__(256) void attn_kernel(const float* __restrict__ Qp,
                                                   const float* __restrict__ Kp,
                                                   const float* __restrict__ V,
                                                   float* __restrict__ out) {
  __shared__ float Srow[ROWS * 2048];   // 32 KB score block (+aliased lists)

  const int tid = threadIdx.x;
  const int w = tid >> 6, l = tid & 63;
  // bijective XCD-chunk swizzle (nwg = 16384, divisible by 8 XCDs)
  const int nwg = BB * HH * (SS / ROWS);
  const int bidx = (int)blockIdx.x;
  const int swz = (bidx & 7) * (nwg >> 3) + (bidx >> 3);
  const int bh = swz >> 9;
  const int rb = swz & 511;
  const int b = bh >> 4, h = bh & 15;
  const int r0 = rb * ROWS;

  // quad-transposed K panel for this (b,h): [16 quads][2048 keys][4 floats]
  const float* Ktb = Kp + (size_t)bh * (16 * 2048 * 4);

  // ----- score phase: each thread handles keys tid + 256*c, c = 0..7 --------
#pragma unroll 1
  for (int c = 0; c < 8; ++c) {
    const int key = tid + c * 256;

    float acc[ROWS][4];                 // [row][sse-lane], static-indexed
#pragma unroll
    for (int r = 0; r < ROWS; ++r)
#pragma unroll
      for (int j = 0; j < 4; ++j) acc[r][j] = 0.f;

#pragma unroll
    for (int g = 0; g < 4; ++g) {       // groups of 16, ascending
      float4 kt[4];                     // one 64B line of K (coalesced loads)
#pragma unroll
      for (int i = 0; i < 4; ++i)
        kt[i] = *(const float4*)(Ktb + (((size_t)(g * 4 + i) * 2048 + key) << 2));
#pragma unroll
      for (int r = 0; r < ROWS; ++r) {
        // wave-uniform Q addresses -> scalar loads
        const float4* qp4 = (const float4*)(Qp + ((size_t)bh * SS + r0 + r) * DA);
        float4 q4[4];
#pragma unroll
        for (int i = 0; i < 4; ++i) q4[i] = qp4[g * 4 + i];
#pragma unroll
        for (int blk = 3; blk >= 0; --blk) {   // 4-blocks DESCENDING in group
          acc[r][0] = __fadd_rn(acc[r][0], __fmul_rn(q4[blk].x, kt[blk].x));
          acc[r][1] = __fadd_rn(acc[r][1], __fmul_rn(q4[blk].y, kt[blk].y));
          acc[r][2] = __fadd_rn(acc[r][2], __fmul_rn(q4[blk].z, kt[blk].z));
          acc[r][3] = __fadd_rn(acc[r][3], __fmul_rn(q4[blk].w, kt[blk].w));
        }
      }
    }
#pragma unroll
    for (int r = 0; r < ROWS; ++r) {
      const float s = __fadd_rn(__fadd_rn(acc[r][0], acc[r][1]),
                                __fadd_rn(acc[r][2], acc[r][3]));
      Srow[r * 2048 + key] = s * 0.125f;
    }
  }
  __syncthreads();

  const float* Vh = V + (size_t)b * SS * DD + h * DA;
  float* outh = out + ((size_t)(b * SS + r0 + w)) * DD + h * DA;

  // ----- per-wave: one row (r = w): exact top-32, softmax, sparse PV --------
  {
    const int r = w;
    float sv[32];
#pragma unroll
    for (int i = 0; i < 32; ++i) sv[i] = Srow[r * 2048 + 64 * i + l];
    // From here on, this wave's Srow slice is dead: reuse the first 128
    // floats of it as the survivor (weight,key) lists.
    float* wl = &Srow[r * 2048];        // [0..63]  survivor weights
    float* kl = &Srow[r * 2048 + 64];   // [64..127] survivor keys (bit-punned)

    float mx = sv[0], mn = sv[0];
#pragma unroll
    for (int i = 1; i < 32; ++i) { mx = fmaxf(mx, sv[i]); mn = fminf(mn, sv[i]); }
#pragma unroll
    for (int off = 32; off >= 1; off >>= 1) {
      mx = fmaxf(mx, __shfl_xor(mx, off));
      mn = fminf(mn, __shfl_xor(mn, off));
    }

    // bisection for the exact 32nd-largest score value.
    float lo = mn, hi = mx + 1.0f;
    float cutoff = mn;
    for (int it = 0; ; ++it) {
      const float mid = 0.5f * (lo + hi);
      if (it >= 64 || !(mid > lo && mid < hi)) { cutoff = lo; break; }
      int c = 0;
#pragma unroll
      for (int i = 0; i < 32; ++i)
        c += (int)__popcll(__ballot(sv[i] >= mid));
      if (c == TOPK) {
        float cm = 3.0e38f;
#pragma unroll
        for (int i = 0; i < 32; ++i) if (sv[i] >= mid) cm = fminf(cm, sv[i]);
#pragma unroll
        for (int off = 32; off >= 1; off >>= 1) cm = fminf(cm, __shfl_xor(cm, off));
        cutoff = cm;
        break;
      }
      if (c > TOPK) lo = mid; else hi = mid;
    }

    // weights on kept entries (ties at cutoff kept, matching scores>=cutoff)
    float wv[32];
    float dpart = 0.f;
    int ckept = 0;
#pragma unroll
    for (int i = 0; i < 32; ++i) {
      const bool keep = (sv[i] >= cutoff);
      ckept += (int)__popcll(__ballot(keep));
      const float e = keep ? __expf(sv[i] - mx) : 0.f;
      wv[i] = e;
      dpart += e;
    }
    float denom = dpart;
#pragma unroll
    for (int off = 32; off >= 1; off >>= 1) denom += __shfl_xor(denom, off);
    const float inv_denom = 1.0f / denom;

    float e = 0.f;
    if (ckept <= 64) {
      // ballot compaction of survivors into the aliased LDS lists (ascending k)
      int base = 0;
#pragma unroll
      for (int i = 0; i < 32; ++i) {
        const unsigned long long mball = __ballot(wv[i] > 0.f);
        if (wv[i] > 0.f) {
          const int pos = base + (int)__popcll(mball & ((1ull << l) - 1ull));
          wl[pos] = wv[i];
          kl[pos] = __int_as_float(64 * i + l);
        }
        base += (int)__popcll(mball);
      }
      asm volatile("s_waitcnt lgkmcnt(0)" ::: "memory");
      // PV gather, batched x8: 8 independent V loads in flight per batch.
      // fma chain order (ascending survivor index) preserved bit-identically.
      int i = 0;
      for (; i + 8 <= ckept; i += 8) {
        float ww[8]; int kk[8];
#pragma unroll
        for (int u = 0; u < 8; ++u) { ww[u] = wl[i + u]; kk[u] = __float_as_int(kl[i + u]); }
        float vv[8];
#pragma unroll
        for (int u = 0; u < 8; ++u) vv[u] = Vh[(size_t)kk[u] * DD + l];
#pragma unroll
        for (int u = 0; u < 8; ++u) e = fmaf(ww[u], vv[u], e);
      }
      for (; i < ckept; ++i) {
        const float ww = wl[i];
        const int kk = __float_as_int(kl[i]);
        e = fmaf(ww, Vh[(size_t)kk * DD + l], e);
      }
    } else {
      // pathological-tie fallback: dense accumulation (own row only)
#pragma unroll
      for (int i = 0; i < 32; ++i) Srow[r * 2048 + 64 * i + l] = wv[i];
      asm volatile("s_waitcnt lgkmcnt(0)" ::: "memory");
      for (int k = 0; k < 2048; ++k) {
        const float ww = Srow[r * 2048 + k];
        if (ww > 0.f) e = fmaf(ww, Vh[(size_t)k * DD + l], e);
      }
    }
    outh[l] = e * inv_denom;
  }
}

extern "C" void kernel_launch(void* const* d_in, const int* in_sizes, int n_in,
                              void* d_out, int out_size, void* d_ws, size_t ws_size,
                              hipStream_t stream) {
  const float* query = (const float*)d_in[0];
  const float* key   = (const float*)d_in[1];
  const float* value = (const float*)d_in[2];
  const float* Wq    = (const float*)d_in[3];
  const float* Wk    = (const float*)d_in[4];
  float* out = (float*)d_out;

  float* Qp = (float*)d_ws;                                  // 16.8 MB
  float* Kp = Qp + (size_t)BB * HH * SS * DA;                // 16.8 MB (transposed)

  proj_kernel<<<dim3(16, 64, 2), 256, 0, stream>>>(query, Wq, Qp, key, Wk, Kp);
  attn_kernel<<<dim3(BB * HH * (SS / ROWS)), 256, 0, stream>>>(Qp, Kp, value, out);
}